// Round 2
// baseline (429.617 us; speedup 1.0000x reference)
//
#include <hip/hip_runtime.h>

#define T_SEQ 4096
#define C_EMB 2048
#define NH 16
#define NKV 4
#define HD 128

typedef short bf16x8 __attribute__((ext_vector_type(8)));
typedef float f32x4 __attribute__((ext_vector_type(4)));
typedef unsigned short u16x4 __attribute__((ext_vector_type(4)));

__device__ inline unsigned short f2bf(float f) {
    unsigned int u = __float_as_uint(f);
    unsigned int r = (u + 0x7FFFu + ((u >> 16) & 1u)) >> 16;
    return (unsigned short)r;
}

// async global->LDS 16B per lane; lds base must be wave-uniform (lane*16 auto-added)
__device__ __forceinline__ void async_cp16(const unsigned short* g, unsigned short* l) {
    __builtin_amdgcn_global_load_lds((const __attribute__((address_space(1))) unsigned int*)g,
                                     (__attribute__((address_space(3))) unsigned int*)l,
                                     16, 0, 0);
}

// ---------------- fp32 -> bf16 elementwise ----------------
__global__ __launch_bounds__(256) void cvt_bf16(const float* __restrict__ in,
                                                unsigned short* __restrict__ out, int n) {
    int i = (blockIdx.x * 256 + threadIdx.x) * 4;
    if (i >= n) return;
    float4 f = *(const float4*)(&in[i]);
    u16x4 o;
    o.x = f2bf(f.x); o.y = f2bf(f.y); o.z = f2bf(f.z); o.w = f2bf(f.w);
    *(u16x4*)(&out[i]) = o;
}

// ---------------- merged weight transposes: 4 matrices in one launch ----------------
__global__ __launch_bounds__(256) void transpose_all(const float* __restrict__ wq,
                                                     const float* __restrict__ wk,
                                                     const float* __restrict__ wv,
                                                     const float* __restrict__ wo,
                                                     unsigned short* __restrict__ wqkvT,
                                                     unsigned short* __restrict__ woT) {
    __shared__ float tile[32][33];
    int z = blockIdx.z;
    const float* in;
    unsigned short* out;
    int ld_in;
    if (z == 0)      { in = wq; out = wqkvT;                         ld_in = 2048; }
    else if (z == 1) { in = wk; out = wqkvT + (size_t)2048 * 2048;   ld_in = 512;  }
    else if (z == 2) { in = wv; out = wqkvT + (size_t)2560 * 2048;   ld_in = 512;  }
    else             { in = wo; out = woT;                           ld_in = 2048; }
    if ((z == 1 || z == 2) && blockIdx.x >= 16) return;

    int x = blockIdx.x * 32 + threadIdx.x;
    for (int i = threadIdx.y; i < 32; i += 8) {
        int y = blockIdx.y * 32 + i;
        tile[i][threadIdx.x] = in[(size_t)y * ld_in + x];
    }
    __syncthreads();
    int xo = blockIdx.y * 32 + threadIdx.x;
    for (int i = threadIdx.y; i < 32; i += 8) {
        int yo = blockIdx.x * 32 + i;
        out[(size_t)yo * 2048 + xo] = f2bf(tile[threadIdx.x][i]);
    }
}

// ==== Fused QKV projection + RoPE + RMSNorm + V-transpose ====
// 128x128 tile, BK=32 double-buffered (32KB LDS -> 4 blocks/CU), one barrier/iter.
// Wave tiling 1x4 (wave w: rows w*32..w*32+31, all 128 cols).
__global__ __launch_bounds__(256, 4) void gemm_qkv(const unsigned short* __restrict__ A,
                                                   const unsigned short* __restrict__ Bt,
                                                   const float* __restrict__ cosb,
                                                   const float* __restrict__ sinb,
                                                   unsigned short* __restrict__ Qn,
                                                   unsigned short* __restrict__ Kn,
                                                   unsigned short* __restrict__ Vt) {
    __shared__ __align__(16) unsigned short As[2][128 * 32];
    __shared__ __align__(16) unsigned short Bs[2][128 * 32];
    const int K = 2048;
    int t = threadIdx.x;
    int w = t >> 6, lane = t & 63;
    int ln = lane & 15, q = lane >> 4;
    int wm = w * 32;
    int m0 = blockIdx.y * 128, n0 = blockIdx.x * 128;

    f32x4 acc[2][8] = {};

#pragma unroll
    for (int s = 0; s < 2; ++s) {
        int L = s * 256 + t;
        int r = L >> 2;
        int c = (L & 3) ^ ((L >> 4) & 3);
        async_cp16(&A[(size_t)(m0 + r) * K + c * 8], &As[0][s * 2048 + w * 512]);
        async_cp16(&Bt[(size_t)(n0 + r) * K + c * 8], &Bs[0][s * 2048 + w * 512]);
    }

    for (int it = 0; it < 64; ++it) {
        __syncthreads();
        if (it < 63) {
            int k0 = (it + 1) * 32;
            int p = (it + 1) & 1;
#pragma unroll
            for (int s = 0; s < 2; ++s) {
                int L = s * 256 + t;
                int r = L >> 2;
                int c = (L & 3) ^ ((L >> 4) & 3);
                async_cp16(&A[(size_t)(m0 + r) * K + k0 + c * 8], &As[p][s * 2048 + w * 512]);
                async_cp16(&Bt[(size_t)(n0 + r) * K + k0 + c * 8], &Bs[p][s * 2048 + w * 512]);
            }
        }
        int p = it & 1;
        int cs = (q ^ ((ln >> 2) & 3)) * 8;
        bf16x8 af[2], bfr[8];
#pragma unroll
        for (int i = 0; i < 2; ++i) af[i] = *(const bf16x8*)(&As[p][(wm + i * 16 + ln) * 32 + cs]);
#pragma unroll
        for (int j = 0; j < 8; ++j) bfr[j] = *(const bf16x8*)(&Bs[p][(j * 16 + ln) * 32 + cs]);
#pragma unroll
        for (int i = 0; i < 2; ++i)
#pragma unroll
            for (int j = 0; j < 8; ++j)
                acc[i][j] = __builtin_amdgcn_mfma_f32_16x16x32_bf16(af[i], bfr[j], acc[i][j], 0, 0, 0);
    }

    // ---- fused epilogue ----
    if (n0 < 2560) {
        bool isQ = (n0 < 2048);
        int h = isQ ? (n0 >> 7) : ((n0 - 2048) >> 7);
#pragma unroll
        for (int i = 0; i < 2; ++i)
#pragma unroll
            for (int r = 0; r < 4; ++r) {
                int row = m0 + wm + i * 16 + q * 4 + r;
                float y1[4], y2[4];
                float ss = 0.0f;
#pragma unroll
                for (int j = 0; j < 4; ++j) {
                    float a = acc[i][j][r];
                    float b = acc[i][j + 4][r];
                    float cc = cosb[row * 64 + j * 16 + ln];
                    float sv = sinb[row * 64 + j * 16 + ln];
                    y1[j] = a * cc + b * sv;
                    y2[j] = b * cc - a * sv;
                    ss += y1[j] * y1[j] + y2[j] * y2[j];
                }
                ss += __shfl_xor(ss, 1);
                ss += __shfl_xor(ss, 2);
                ss += __shfl_xor(ss, 4);
                ss += __shfl_xor(ss, 8);
                float rv = rsqrtf(ss * (1.0f / 128.0f) + 1e-6f);
                if (isQ) {
                    float s = rv * (0.08838834764831845f * 1.4426950408889634f);
                    unsigned short* ob = Qn + (size_t)row * 2048 + h * 128;
#pragma unroll
                    for (int j = 0; j < 4; ++j) {
                        ob[j * 16 + ln] = f2bf(y1[j] * s);
                        ob[64 + j * 16 + ln] = f2bf(y2[j] * s);
                    }
                } else {
                    unsigned short* ob = Kn + (size_t)row * 512 + h * 128;
#pragma unroll
                    for (int j = 0; j < 4; ++j) {
                        ob[j * 16 + ln] = f2bf(y1[j] * rv);
                        ob[64 + j * 16 + ln] = f2bf(y2[j] * rv);
                    }
                }
            }
    } else {
        // V: transpose via LDS scratch (pitch 136 shorts = 272B, 16B-aligned rows),
        // 2 halves of 64 cols. Scratch spans As[0..]+Bs head: 8704 shorts < 16384.
        int v0 = n0 - 2560;
        unsigned short* sm = &As[0][0];
#pragma unroll
        for (int half = 0; half < 2; ++half) {
            __syncthreads();
#pragma unroll
            for (int i = 0; i < 2; ++i)
#pragma unroll
                for (int jj = 0; jj < 4; ++jj) {
                    int j = half * 4 + jj;
                    int cc = jj * 16 + ln;
                    int rr = wm + i * 16 + q * 4;
                    u16x4 pk;
                    pk.x = f2bf(acc[i][j][0]); pk.y = f2bf(acc[i][j][1]);
                    pk.z = f2bf(acc[i][j][2]); pk.w = f2bf(acc[i][j][3]);
                    *(u16x4*)(&sm[cc * 136 + rr]) = pk;
                }
            __syncthreads();
            // coalesced write out: 64 vt-rows x 128 m; each thread owns 32 shorts
            int vtr = t >> 2, mseg = (t & 3) * 32;
            unsigned short* dst = Vt + (size_t)(v0 + half * 64 + vtr) * 4096 + m0 + mseg;
            const unsigned short* src = &sm[vtr * 136 + mseg];
            *(int4*)(dst)      = *(const int4*)(src);
            *(int4*)(dst + 8)  = *(const int4*)(src + 8);
            *(int4*)(dst + 16) = *(const int4*)(src + 16);
            *(int4*)(dst + 24) = *(const int4*)(src + 24);
        }
    }
}

// ---------------- bf16 GEMM (out-proj): 128x128, BK=32 dbuf, 4 blocks/CU ----------------
__global__ __launch_bounds__(256, 4) void gemm_bt_db(const unsigned short* __restrict__ A,
                                                     const unsigned short* __restrict__ Bt,
                                                     float* __restrict__ C, int M, int N, int K) {
    __shared__ __align__(16) unsigned short As[2][128 * 32];
    __shared__ __align__(16) unsigned short Bs[2][128 * 32];
    int t = threadIdx.x;
    int w = t >> 6, lane = t & 63;
    int ln = lane & 15, q = lane >> 4;
    int wm = (w >> 1) * 64, wn = (w & 1) * 64;
    int m0 = blockIdx.y * 128, n0 = blockIdx.x * 128;

    f32x4 acc[4][4] = {};

#pragma unroll
    for (int s = 0; s < 2; ++s) {
        int L = s * 256 + t;
        int r = L >> 2;
        int c = (L & 3) ^ ((L >> 4) & 3);
        async_cp16(&A[(size_t)(m0 + r) * K + c * 8], &As[0][s * 2048 + w * 512]);
        async_cp16(&Bt[(size_t)(n0 + r) * K + c * 8], &Bs[0][s * 2048 + w * 512]);
    }

    int niter = K >> 5;
    for (int it = 0; it < niter; ++it) {
        __syncthreads();
        if (it < niter - 1) {
            int k0 = (it + 1) * 32;
            int p = (it + 1) & 1;
#pragma unroll
            for (int s = 0; s < 2; ++s) {
                int L = s * 256 + t;
                int r = L >> 2;
                int c = (L & 3) ^ ((L >> 4) & 3);
                async_cp16(&A[(size_t)(m0 + r) * K + k0 + c * 8], &As[p][s * 2048 + w * 512]);
                async_cp16(&Bt[(size_t)(n0 + r) * K + k0 + c * 8], &Bs[p][s * 2048 + w * 512]);
            }
        }
        int p = it & 1;
        int cs = (q ^ ((ln >> 2) & 3)) * 8;
        bf16x8 af[4], bfr[4];
#pragma unroll
        for (int i = 0; i < 4; ++i) af[i] = *(const bf16x8*)(&As[p][(wm + i * 16 + ln) * 32 + cs]);
#pragma unroll
        for (int j = 0; j < 4; ++j) bfr[j] = *(const bf16x8*)(&Bs[p][(wn + j * 16 + ln) * 32 + cs]);
#pragma unroll
        for (int i = 0; i < 4; ++i)
#pragma unroll
            for (int j = 0; j < 4; ++j)
                acc[i][j] = __builtin_amdgcn_mfma_f32_16x16x32_bf16(af[i], bfr[j], acc[i][j], 0, 0, 0);
    }
#pragma unroll
    for (int i = 0; i < 4; ++i)
#pragma unroll
        for (int j = 0; j < 4; ++j)
#pragma unroll
            for (int r = 0; r < 4; ++r) {
                int row = m0 + wm + i * 16 + q * 4 + r;
                int col = n0 + wn + j * 16 + ln;
                C[(size_t)row * N + col] = acc[i][j][r];
            }
}

// ---------------- Flash attention v6: 32 q-rows/wave, KVBLK=32, unpaired ----------------
// 2 waves x 32 rows = 64 q-rows/block; one q-block per block (no pairing) so
// 1024 blocks x 2 waves = 2048 waves = 8 waves/CU (LDS 37888B -> 4 blocks/CU).
// Each K/V LDS fragment feeds 2 MFMAs (halved LDS read traffic vs 16-row waves).
// Longest blocks launch first (bq = 63 - blockIdx.x) for tail packing.
__global__ __launch_bounds__(128) void flash_attn(const unsigned short* __restrict__ Qn,
                                                  const unsigned short* __restrict__ Kn,
                                                  const unsigned short* __restrict__ Vt,
                                                  unsigned short* __restrict__ Ao) {
    __shared__ __align__(16) unsigned short Ks[2][32 * 128];   // 16 KB
    __shared__ __align__(16) unsigned short Vs[2][128 * 32];   // 16 KB
    __shared__ __align__(16) unsigned short Pl[2][32 * 40];    // 5 KB, pitch 40 (80B, 16B-mult)

    int bq = 63 - blockIdx.x;          // descending work order
    int h = blockIdx.y;
    int kvh = h >> 2;
    int t = threadIdx.x;
    int w = t >> 6, lane = t & 63;
    int ln = lane & 15, q = lane >> 4;

    int wq0 = bq * 64 + w * 32;
    int niter = 2 * bq + 2;            // 32-key tiles covering keys 0..bq*64+63

    bf16x8 qf[2][4];
#pragma unroll
    for (int i = 0; i < 2; ++i) {
        const unsigned short* qb = Qn + (size_t)(wq0 + i * 16 + ln) * 2048 + h * 128;
#pragma unroll
        for (int kc = 0; kc < 4; ++kc) qf[i][kc] = *(const bf16x8*)(qb + kc * 32 + q * 8);
    }

    f32x4 o[2][8] = {};
    f32x4 l_p[2] = {};

    // stage tile 0
#pragma unroll
    for (int s = 0; s < 4; ++s) {
        int L = s * 128 + t;
        int key = L >> 4;
        int c = (L & 15) ^ (key & 15);
        async_cp16(Kn + (size_t)key * 512 + kvh * 128 + c * 8, &Ks[0][s * 1024 + w * 512]);
    }
#pragma unroll
    for (int s = 0; s < 4; ++s) {
        int L = s * 128 + t;
        int hd = L >> 2;
        int c = (L & 3) ^ (hd & 3);
        async_cp16(Vt + (size_t)(kvh * 128 + hd) * 4096 + c * 8, &Vs[0][s * 1024 + w * 512]);
    }

    for (int it = 0; it < niter; ++it) {
        __syncthreads();

        int nxt = it + 1;
        if (nxt < niter) {
            int nkt = nxt * 32;
            unsigned short* kd = Ks[nxt & 1];
            unsigned short* vd = Vs[nxt & 1];
#pragma unroll
            for (int s = 0; s < 4; ++s) {
                int L = s * 128 + t;
                int key = L >> 4;
                int c = (L & 15) ^ (key & 15);
                async_cp16(Kn + (size_t)(nkt + key) * 512 + kvh * 128 + c * 8,
                           kd + s * 1024 + w * 512);
            }
#pragma unroll
            for (int s = 0; s < 4; ++s) {
                int L = s * 128 + t;
                int hd = L >> 2;
                int c = (L & 3) ^ (hd & 3);
                async_cp16(Vt + (size_t)(kvh * 128 + hd) * 4096 + nkt + c * 8,
                           vd + s * 1024 + w * 512);
            }
        }

        int kt0 = it * 32;
        const unsigned short* kb = Ks[it & 1];
        const unsigned short* vb = Vs[it & 1];

        // QK^T: 2 row tiles x 2 key tiles; each K fragment feeds both row tiles
        f32x4 sA[2][2];
#pragma unroll
        for (int i = 0; i < 2; ++i)
#pragma unroll
            for (int jt = 0; jt < 2; ++jt)
                sA[i][jt] = (f32x4){-16.6f, -16.6f, -16.6f, -16.6f};

#pragma unroll
        for (int jt = 0; jt < 2; ++jt) {
            int key = jt * 16 + ln;
#pragma unroll
            for (int kc = 0; kc < 4; ++kc) {
                int cs = ((kc * 4 + q) ^ ln) * 8;
                bf16x8 kf = *(const bf16x8*)(&kb[key * 128 + cs]);
                sA[0][jt] = __builtin_amdgcn_mfma_f32_16x16x32_bf16(qf[0][kc], kf, sA[0][jt], 0, 0, 0);
                sA[1][jt] = __builtin_amdgcn_mfma_f32_16x16x32_bf16(qf[1][kc], kf, sA[1][jt], 0, 0, 0);
            }
        }
        if (kt0 + 31 > wq0) {
#pragma unroll
            for (int i = 0; i < 2; ++i)
#pragma unroll
                for (int jt = 0; jt < 2; ++jt)
#pragma unroll
                    for (int r = 0; r < 4; ++r) {
                        int key = kt0 + jt * 16 + ln;
                        int row = wq0 + i * 16 + q * 4 + r;
                        if (key > row) sA[i][jt][r] = -3e38f;
                    }
        }
#pragma unroll
        for (int i = 0; i < 2; ++i)
#pragma unroll
            for (int r = 0; r < 4; ++r) {
                int prow = (i * 16 + q * 4 + r) * 40;
#pragma unroll
                for (int jt = 0; jt < 2; ++jt) {
                    float p = __builtin_amdgcn_exp2f(sA[i][jt][r]);
                    Pl[w][prow + jt * 16 + ln] = (unsigned short)(__float_as_uint(p) >> 16);
                    l_p[i][r] += p;
                }
            }

        // PV: k-depth 32 = one MFMA step; each V fragment feeds both row tiles
        bf16x8 pa0 = *(const bf16x8*)(&Pl[w][ln * 40 + q * 8]);
        bf16x8 pa1 = *(const bf16x8*)(&Pl[w][(16 + ln) * 40 + q * 8]);
        int cs = (q ^ (ln & 3)) * 8;
#pragma unroll
        for (int f = 0; f < 8; ++f) {
            bf16x8 vf = *(const bf16x8*)(&vb[(f * 16 + ln) * 32 + cs]);
            o[0][f] = __builtin_amdgcn_mfma_f32_16x16x32_bf16(pa0, vf, o[0][f], 0, 0, 0);
            o[1][f] = __builtin_amdgcn_mfma_f32_16x16x32_bf16(pa1, vf, o[1][f], 0, 0, 0);
        }
    }

#pragma unroll
    for (int i = 0; i < 2; ++i)
#pragma unroll
        for (int r = 0; r < 4; ++r) {
            float lsum = l_p[i][r];
            lsum += __shfl_xor(lsum, 1);
            lsum += __shfl_xor(lsum, 2);
            lsum += __shfl_xor(lsum, 4);
            lsum += __shfl_xor(lsum, 8);
            float inv = 1.0f / lsum;
            int row = wq0 + i * 16 + q * 4 + r;
            unsigned short* ob = Ao + (size_t)row * 2048 + h * 128;
#pragma unroll
            for (int f = 0; f < 8; ++f) ob[f * 16 + ln] = f2bf(o[i][f][r] * inv);
        }
}

extern "C" void kernel_launch(void* const* d_in, const int* in_sizes, int n_in,
                              void* d_out, int out_size, void* d_ws, size_t ws_size,
                              hipStream_t stream) {
    const float* x    = (const float*)d_in[0];
    const float* cosb = (const float*)d_in[1];
    const float* sinb = (const float*)d_in[2];
    const float* wq   = (const float*)d_in[3];
    const float* wk   = (const float*)d_in[4];
    const float* wv   = (const float*)d_in[5];
    const float* wo   = (const float*)d_in[6];
    float* out = (float*)d_out;

    char* ws = (char*)d_ws;
    unsigned short* xb    = (unsigned short*)ws;               // [4096][2048]
    unsigned short* wqkvT = xb    + (size_t)4096 * 2048;       // [3072][2048]
    unsigned short* woT   = wqkvT + (size_t)3072 * 2048;       // [2048][2048]
    unsigned short* Qn    = woT   + (size_t)2048 * 2048;       // [4096][2048]
    unsigned short* Kn    = Qn    + (size_t)4096 * 2048;       // [4096][512]
    unsigned short* Vt    = Kn    + (size_t)4096 * 512;        // [512][4096]
    unsigned short* Ao    = Vt    + (size_t)512 * 4096;        // [4096][2048]

    cvt_bf16<<<(4096 * 2048 / 4 + 255) / 256, 256, 0, stream>>>(x, xb, 4096 * 2048);
    transpose_all<<<dim3(64, 64, 4), dim3(32, 8), 0, stream>>>(wq, wk, wv, wo, wqkvT, woT);
    gemm_qkv<<<dim3(24, 32), 256, 0, stream>>>(xb, wqkvT, cosb, sinb, Qn, Kn, Vt);
    flash_attn<<<dim3(64, 16), 128, 0, stream>>>(Qn, Kn, Vt, Ao);
    gemm_bt_db<<<dim3(16, 32), 256, 0, stream>>>(Ao, woT, out, 4096, 2048, 2048);
}

// Round 3
// 355.720 us; speedup vs baseline: 1.2077x; 1.2077x over previous
//
#include <hip/hip_runtime.h>

#define T_SEQ 4096
#define C_EMB 2048
#define NH 16
#define NKV 4
#define HD 128

typedef short bf16x8 __attribute__((ext_vector_type(8)));
typedef float f32x4 __attribute__((ext_vector_type(4)));
typedef unsigned short u16x4 __attribute__((ext_vector_type(4)));

__device__ inline unsigned short f2bf(float f) {
    unsigned int u = __float_as_uint(f);
    unsigned int r = (u + 0x7FFFu + ((u >> 16) & 1u)) >> 16;
    return (unsigned short)r;
}

// async global->LDS 16B per lane; lds base must be wave-uniform (lane*16 auto-added)
__device__ __forceinline__ void async_cp16(const unsigned short* g, unsigned short* l) {
    __builtin_amdgcn_global_load_lds((const __attribute__((address_space(1))) unsigned int*)g,
                                     (__attribute__((address_space(3))) unsigned int*)l,
                                     16, 0, 0);
}

// ---------------- fp32 -> bf16 elementwise ----------------
__global__ __launch_bounds__(256) void cvt_bf16(const float* __restrict__ in,
                                                unsigned short* __restrict__ out, int n) {
    int i = (blockIdx.x * 256 + threadIdx.x) * 4;
    if (i >= n) return;
    float4 f = *(const float4*)(&in[i]);
    u16x4 o;
    o.x = f2bf(f.x); o.y = f2bf(f.y); o.z = f2bf(f.z); o.w = f2bf(f.w);
    *(u16x4*)(&out[i]) = o;
}

// ---------------- merged weight transposes: 4 matrices in one launch ----------------
__global__ __launch_bounds__(256) void transpose_all(const float* __restrict__ wq,
                                                     const float* __restrict__ wk,
                                                     const float* __restrict__ wv,
                                                     const float* __restrict__ wo,
                                                     unsigned short* __restrict__ wqkvT,
                                                     unsigned short* __restrict__ woT) {
    __shared__ float tile[32][33];
    int z = blockIdx.z;
    const float* in;
    unsigned short* out;
    int ld_in;
    if (z == 0)      { in = wq; out = wqkvT;                         ld_in = 2048; }
    else if (z == 1) { in = wk; out = wqkvT + (size_t)2048 * 2048;   ld_in = 512;  }
    else if (z == 2) { in = wv; out = wqkvT + (size_t)2560 * 2048;   ld_in = 512;  }
    else             { in = wo; out = woT;                           ld_in = 2048; }
    if ((z == 1 || z == 2) && blockIdx.x >= 16) return;

    int x = blockIdx.x * 32 + threadIdx.x;
    for (int i = threadIdx.y; i < 32; i += 8) {
        int y = blockIdx.y * 32 + i;
        tile[i][threadIdx.x] = in[(size_t)y * ld_in + x];
    }
    __syncthreads();
    int xo = blockIdx.y * 32 + threadIdx.x;
    for (int i = threadIdx.y; i < 32; i += 8) {
        int yo = blockIdx.x * 32 + i;
        out[(size_t)yo * 2048 + xo] = f2bf(tile[threadIdx.x][i]);
    }
}

// ==== Fused QKV projection + RoPE + RMSNorm + V-transpose ====
// v7: 128x128 tile, BK=64 double-buffered (64KB LDS -> 2 blocks/CU = 8 waves/CU),
// m97-class structure: 32 K-iters (half the barrier drains of BK=32), 4 cp16/thread/matrix
// prefetch depth, 8-deep XOR swizzle (16B chunk ^= row&7) on 128B-pitch rows.
// Wave tiling 1x4 (wave w: rows w*32..w*32+31, all 128 cols). Epilogue unchanged.
__global__ __launch_bounds__(256, 2) void gemm_qkv(const unsigned short* __restrict__ A,
                                                   const unsigned short* __restrict__ Bt,
                                                   const float* __restrict__ cosb,
                                                   const float* __restrict__ sinb,
                                                   unsigned short* __restrict__ Qn,
                                                   unsigned short* __restrict__ Kn,
                                                   unsigned short* __restrict__ Vt) {
    __shared__ __align__(16) unsigned short As[2][128 * 64];
    __shared__ __align__(16) unsigned short Bs[2][128 * 64];
    const int K = 2048;
    int t = threadIdx.x;
    int w = t >> 6, lane = t & 63;
    int ln = lane & 15, q = lane >> 4;
    int wm = w * 32;
    int m0 = blockIdx.y * 128, n0 = blockIdx.x * 128;

    f32x4 acc[2][8] = {};

#pragma unroll
    for (int s = 0; s < 4; ++s) {
        int L = s * 256 + t;
        int r = L >> 3;
        int c = (L & 7) ^ (r & 7);
        async_cp16(&A[(size_t)(m0 + r) * K + c * 8], &As[0][s * 2048 + w * 512]);
        async_cp16(&Bt[(size_t)(n0 + r) * K + c * 8], &Bs[0][s * 2048 + w * 512]);
    }

    for (int it = 0; it < 32; ++it) {
        __syncthreads();
        if (it < 31) {
            int k0 = (it + 1) * 64;
            int p = (it + 1) & 1;
#pragma unroll
            for (int s = 0; s < 4; ++s) {
                int L = s * 256 + t;
                int r = L >> 3;
                int c = (L & 7) ^ (r & 7);
                async_cp16(&A[(size_t)(m0 + r) * K + k0 + c * 8], &As[p][s * 2048 + w * 512]);
                async_cp16(&Bt[(size_t)(n0 + r) * K + k0 + c * 8], &Bs[p][s * 2048 + w * 512]);
            }
        }
        int p = it & 1;
#pragma unroll
        for (int kk = 0; kk < 2; ++kk) {
            bf16x8 af[2], bfr[8];
#pragma unroll
            for (int i = 0; i < 2; ++i) {
                int row = wm + i * 16 + ln;
                int ch = (kk * 4 + q) ^ (row & 7);
                af[i] = *(const bf16x8*)(&As[p][row * 64 + ch * 8]);
            }
#pragma unroll
            for (int j = 0; j < 8; ++j) {
                int row = j * 16 + ln;
                int ch = (kk * 4 + q) ^ (row & 7);
                bfr[j] = *(const bf16x8*)(&Bs[p][row * 64 + ch * 8]);
            }
#pragma unroll
            for (int i = 0; i < 2; ++i)
#pragma unroll
                for (int j = 0; j < 8; ++j)
                    acc[i][j] = __builtin_amdgcn_mfma_f32_16x16x32_bf16(af[i], bfr[j], acc[i][j], 0, 0, 0);
        }
    }

    // ---- fused epilogue ----
    if (n0 < 2560) {
        bool isQ = (n0 < 2048);
        int h = isQ ? (n0 >> 7) : ((n0 - 2048) >> 7);
#pragma unroll
        for (int i = 0; i < 2; ++i)
#pragma unroll
            for (int r = 0; r < 4; ++r) {
                int row = m0 + wm + i * 16 + q * 4 + r;
                float y1[4], y2[4];
                float ss = 0.0f;
#pragma unroll
                for (int j = 0; j < 4; ++j) {
                    float a = acc[i][j][r];
                    float b = acc[i][j + 4][r];
                    float cc = cosb[row * 64 + j * 16 + ln];
                    float sv = sinb[row * 64 + j * 16 + ln];
                    y1[j] = a * cc + b * sv;
                    y2[j] = b * cc - a * sv;
                    ss += y1[j] * y1[j] + y2[j] * y2[j];
                }
                ss += __shfl_xor(ss, 1);
                ss += __shfl_xor(ss, 2);
                ss += __shfl_xor(ss, 4);
                ss += __shfl_xor(ss, 8);
                float rv = rsqrtf(ss * (1.0f / 128.0f) + 1e-6f);
                if (isQ) {
                    float s = rv * (0.08838834764831845f * 1.4426950408889634f);
                    unsigned short* ob = Qn + (size_t)row * 2048 + h * 128;
#pragma unroll
                    for (int j = 0; j < 4; ++j) {
                        ob[j * 16 + ln] = f2bf(y1[j] * s);
                        ob[64 + j * 16 + ln] = f2bf(y2[j] * s);
                    }
                } else {
                    unsigned short* ob = Kn + (size_t)row * 512 + h * 128;
#pragma unroll
                    for (int j = 0; j < 4; ++j) {
                        ob[j * 16 + ln] = f2bf(y1[j] * rv);
                        ob[64 + j * 16 + ln] = f2bf(y2[j] * rv);
                    }
                }
            }
    } else {
        // V: transpose via LDS scratch (pitch 136 shorts = 272B, 16B-aligned rows),
        // 2 halves of 64 cols. Scratch 8704 shorts fits in As (16384 shorts).
        int v0 = n0 - 2560;
        unsigned short* sm = &As[0][0];
#pragma unroll
        for (int half = 0; half < 2; ++half) {
            __syncthreads();
#pragma unroll
            for (int i = 0; i < 2; ++i)
#pragma unroll
                for (int jj = 0; jj < 4; ++jj) {
                    int j = half * 4 + jj;
                    int cc = jj * 16 + ln;
                    int rr = wm + i * 16 + q * 4;
                    u16x4 pk;
                    pk.x = f2bf(acc[i][j][0]); pk.y = f2bf(acc[i][j][1]);
                    pk.z = f2bf(acc[i][j][2]); pk.w = f2bf(acc[i][j][3]);
                    *(u16x4*)(&sm[cc * 136 + rr]) = pk;
                }
            __syncthreads();
            // coalesced write out: 64 vt-rows x 128 m; each thread owns 32 shorts
            int vtr = t >> 2, mseg = (t & 3) * 32;
            unsigned short* dst = Vt + (size_t)(v0 + half * 64 + vtr) * 4096 + m0 + mseg;
            const unsigned short* src = &sm[vtr * 136 + mseg];
            *(int4*)(dst)      = *(const int4*)(src);
            *(int4*)(dst + 8)  = *(const int4*)(src + 8);
            *(int4*)(dst + 16) = *(const int4*)(src + 16);
            *(int4*)(dst + 24) = *(const int4*)(src + 24);
        }
    }
}

// ---------------- bf16 GEMM (out-proj): 128x128, BK=64 dbuf, 2 blocks/CU ----------------
__global__ __launch_bounds__(256, 2) void gemm_bt_db(const unsigned short* __restrict__ A,
                                                     const unsigned short* __restrict__ Bt,
                                                     float* __restrict__ C, int M, int N, int K) {
    __shared__ __align__(16) unsigned short As[2][128 * 64];
    __shared__ __align__(16) unsigned short Bs[2][128 * 64];
    int t = threadIdx.x;
    int w = t >> 6, lane = t & 63;
    int ln = lane & 15, q = lane >> 4;
    int wm = (w >> 1) * 64, wn = (w & 1) * 64;
    int m0 = blockIdx.y * 128, n0 = blockIdx.x * 128;

    f32x4 acc[4][4] = {};

#pragma unroll
    for (int s = 0; s < 4; ++s) {
        int L = s * 256 + t;
        int r = L >> 3;
        int c = (L & 7) ^ (r & 7);
        async_cp16(&A[(size_t)(m0 + r) * K + c * 8], &As[0][s * 2048 + w * 512]);
        async_cp16(&Bt[(size_t)(n0 + r) * K + c * 8], &Bs[0][s * 2048 + w * 512]);
    }

    int niter = K >> 6;
    for (int it = 0; it < niter; ++it) {
        __syncthreads();
        if (it < niter - 1) {
            int k0 = (it + 1) * 64;
            int p = (it + 1) & 1;
#pragma unroll
            for (int s = 0; s < 4; ++s) {
                int L = s * 256 + t;
                int r = L >> 3;
                int c = (L & 7) ^ (r & 7);
                async_cp16(&A[(size_t)(m0 + r) * K + k0 + c * 8], &As[p][s * 2048 + w * 512]);
                async_cp16(&Bt[(size_t)(n0 + r) * K + k0 + c * 8], &Bs[p][s * 2048 + w * 512]);
            }
        }
        int p = it & 1;
#pragma unroll
        for (int kk = 0; kk < 2; ++kk) {
            bf16x8 af[4], bfr[4];
#pragma unroll
            for (int i = 0; i < 4; ++i) {
                int row = wm + i * 16 + ln;
                int ch = (kk * 4 + q) ^ (row & 7);
                af[i] = *(const bf16x8*)(&As[p][row * 64 + ch * 8]);
            }
#pragma unroll
            for (int j = 0; j < 4; ++j) {
                int row = wn + j * 16 + ln;
                int ch = (kk * 4 + q) ^ (row & 7);
                bfr[j] = *(const bf16x8*)(&Bs[p][row * 64 + ch * 8]);
            }
#pragma unroll
            for (int i = 0; i < 4; ++i)
#pragma unroll
                for (int j = 0; j < 4; ++j)
                    acc[i][j] = __builtin_amdgcn_mfma_f32_16x16x32_bf16(af[i], bfr[j], acc[i][j], 0, 0, 0);
        }
    }
#pragma unroll
    for (int i = 0; i < 4; ++i)
#pragma unroll
        for (int j = 0; j < 4; ++j)
#pragma unroll
            for (int r = 0; r < 4; ++r) {
                int row = m0 + wm + i * 16 + q * 4 + r;
                int col = n0 + wn + j * 16 + ln;
                C[(size_t)row * N + col] = acc[i][j][r];
            }
}

// ---------------- Flash attention v4: fixed-max softmax (reverted, known-good) ----------------
__global__ __launch_bounds__(256) void flash_attn(const unsigned short* __restrict__ Qn,
                                                  const unsigned short* __restrict__ Kn,
                                                  const unsigned short* __restrict__ Vt,
                                                  unsigned short* __restrict__ Ao) {
    __shared__ __align__(16) unsigned short Ks[2][64 * 128];
    __shared__ __align__(16) unsigned short Vs[2][128 * 64];
    __shared__ __align__(16) unsigned short Pl[4][16 * 72];

    int pairi = blockIdx.x;
    int h = blockIdx.y;
    int kvh = h >> 2;
    int t = threadIdx.x;
    int w = t >> 6, lane = t & 63;
    int ln = lane & 15, q = lane >> 4;

    int nA = 64 - pairi;
    int bq = 63 - pairi;
    int wq0 = bq * 64 + w * 16;

    bf16x8 qf[4];
    {
        const unsigned short* qb = Qn + (size_t)(wq0 + ln) * 2048 + h * 128;
#pragma unroll
        for (int kc = 0; kc < 4; ++kc) qf[kc] = *(const bf16x8*)(qb + kc * 32 + q * 8);
    }

    f32x4 o[8] = {};
    f32x4 l_p = {0.f, 0.f, 0.f, 0.f};

#pragma unroll
    for (int s = 0; s < 4; ++s) {
        int L = s * 256 + t;
        int key = L >> 4;
        int c = (L & 15) ^ (key & 15);
        async_cp16(Kn + (size_t)key * 512 + kvh * 128 + c * 8, &Ks[0][s * 2048 + w * 512]);
    }
#pragma unroll
    for (int s = 0; s < 4; ++s) {
        int L = s * 256 + t;
        int hd = L >> 3;
        int c = (L & 7) ^ (hd & 7);
        async_cp16(Vt + (size_t)(kvh * 128 + hd) * 4096 + c * 8, &Vs[0][s * 2048 + w * 512]);
    }

    for (int it = 0; it < 65; ++it) {
        __syncthreads();

        int nxt = it + 1;
        if (nxt < 65) {
            int nkt = (nxt < nA) ? nxt * 64 : (nxt - nA) * 64;
            unsigned short* kd = Ks[nxt & 1];
            unsigned short* vd = Vs[nxt & 1];
#pragma unroll
            for (int s = 0; s < 4; ++s) {
                int L = s * 256 + t;
                int key = L >> 4;
                int c = (L & 15) ^ (key & 15);
                async_cp16(Kn + (size_t)(nkt + key) * 512 + kvh * 128 + c * 8,
                           kd + s * 2048 + w * 512);
            }
#pragma unroll
            for (int s = 0; s < 4; ++s) {
                int L = s * 256 + t;
                int hd = L >> 3;
                int c = (L & 7) ^ (hd & 7);
                async_cp16(Vt + (size_t)(kvh * 128 + hd) * 4096 + nkt + c * 8,
                           vd + s * 2048 + w * 512);
            }
        }

        if (it == nA) {
#pragma unroll
            for (int r = 0; r < 4; ++r) {
                float lsum = l_p[r];
                lsum += __shfl_xor(lsum, 1);
                lsum += __shfl_xor(lsum, 2);
                lsum += __shfl_xor(lsum, 4);
                lsum += __shfl_xor(lsum, 8);
                float inv = 1.0f / lsum;
                int row = wq0 + q * 4 + r;
                unsigned short* ob = Ao + (size_t)row * 2048 + h * 128;
#pragma unroll
                for (int f = 0; f < 8; ++f) ob[f * 16 + ln] = f2bf(o[f][r] * inv);
            }
            bq = pairi;
            wq0 = bq * 64 + w * 16;
            const unsigned short* qb = Qn + (size_t)(wq0 + ln) * 2048 + h * 128;
#pragma unroll
            for (int kc = 0; kc < 4; ++kc) qf[kc] = *(const bf16x8*)(qb + kc * 32 + q * 8);
#pragma unroll
            for (int f = 0; f < 8; ++f) o[f] = (f32x4){0.f, 0.f, 0.f, 0.f};
            l_p = (f32x4){0.f, 0.f, 0.f, 0.f};
        }

        int kt0 = (it < nA) ? it * 64 : (it - nA) * 64;
        const unsigned short* kb = Ks[it & 1];
        const unsigned short* vb = Vs[it & 1];

        f32x4 sA[4] = {{-16.6f, -16.6f, -16.6f, -16.6f}, {-16.6f, -16.6f, -16.6f, -16.6f},
                       {-16.6f, -16.6f, -16.6f, -16.6f}, {-16.6f, -16.6f, -16.6f, -16.6f}};
#pragma unroll
        for (int jt = 0; jt < 4; ++jt) {
            int key = jt * 16 + ln;
#pragma unroll
            for (int kc = 0; kc < 4; ++kc) {
                int cs = ((kc * 4 + q) ^ ln) * 8;
                bf16x8 kf = *(const bf16x8*)(&kb[key * 128 + cs]);
                sA[jt] = __builtin_amdgcn_mfma_f32_16x16x32_bf16(qf[kc], kf, sA[jt], 0, 0, 0);
            }
        }
        if (kt0 + 63 > wq0) {
#pragma unroll
            for (int jt = 0; jt < 4; ++jt)
#pragma unroll
                for (int r = 0; r < 4; ++r) {
                    int key = kt0 + jt * 16 + ln;
                    int row = wq0 + q * 4 + r;
                    if (key > row) sA[jt][r] = -3e38f;
                }
        }
#pragma unroll
        for (int r = 0; r < 4; ++r) {
            int prow = (q * 4 + r) * 72;
#pragma unroll
            for (int jt = 0; jt < 4; ++jt) {
                float p = __builtin_amdgcn_exp2f(sA[jt][r]);
                Pl[w][prow + jt * 16 + ln] = (unsigned short)(__float_as_uint(p) >> 16);
                l_p[r] += p;
            }
        }

#pragma unroll
        for (int ks = 0; ks < 2; ++ks) {
            bf16x8 pa = *(const bf16x8*)(&Pl[w][ln * 72 + ks * 32 + q * 8]);
            int cs = ((ks * 4 + q) ^ (ln & 7)) * 8;
#pragma unroll
            for (int f = 0; f < 8; ++f) {
                bf16x8 vf = *(const bf16x8*)(&vb[(f * 16 + ln) * 64 + cs]);
                o[f] = __builtin_amdgcn_mfma_f32_16x16x32_bf16(pa, vf, o[f], 0, 0, 0);
            }
        }
    }
#pragma unroll
    for (int r = 0; r < 4; ++r) {
        float lsum = l_p[r];
        lsum += __shfl_xor(lsum, 1);
        lsum += __shfl_xor(lsum, 2);
        lsum += __shfl_xor(lsum, 4);
        lsum += __shfl_xor(lsum, 8);
        float inv = 1.0f / lsum;
        int row = wq0 + q * 4 + r;
        unsigned short* ob = Ao + (size_t)row * 2048 + h * 128;
#pragma unroll
        for (int f = 0; f < 8; ++f) ob[f * 16 + ln] = f2bf(o[f][r] * inv);
    }
}

extern "C" void kernel_launch(void* const* d_in, const int* in_sizes, int n_in,
                              void* d_out, int out_size, void* d_ws, size_t ws_size,
                              hipStream_t stream) {
    const float* x    = (const float*)d_in[0];
    const float* cosb = (const float*)d_in[1];
    const float* sinb = (const float*)d_in[2];
    const float* wq   = (const float*)d_in[3];
    const float* wk   = (const float*)d_in[4];
    const float* wv   = (const float*)d_in[5];
    const float* wo   = (const float*)d_in[6];
    float* out = (float*)d_out;

    char* ws = (char*)d_ws;
    unsigned short* xb    = (unsigned short*)ws;               // [4096][2048]
    unsigned short* wqkvT = xb    + (size_t)4096 * 2048;       // [3072][2048]
    unsigned short* woT   = wqkvT + (size_t)3072 * 2048;       // [2048][2048]
    unsigned short* Qn    = woT   + (size_t)2048 * 2048;       // [4096][2048]
    unsigned short* Kn    = Qn    + (size_t)4096 * 2048;       // [4096][512]
    unsigned short* Vt    = Kn    + (size_t)4096 * 512;        // [512][4096]
    unsigned short* Ao    = Vt    + (size_t)512 * 4096;        // [4096][2048]

    cvt_bf16<<<(4096 * 2048 / 4 + 255) / 256, 256, 0, stream>>>(x, xb, 4096 * 2048);
    transpose_all<<<dim3(64, 64, 4), dim3(32, 8), 0, stream>>>(wq, wk, wv, wo, wqkvT, woT);
    gemm_qkv<<<dim3(24, 32), 256, 0, stream>>>(xb, wqkvT, cosb, sinb, Qn, Kn, Vt);
    flash_attn<<<dim3(32, 16), 256, 0, stream>>>(Qn, Kn, Vt, Ao);
    gemm_bt_db<<<dim3(16, 32), 256, 0, stream>>>(Ao, woT, out, 4096, 2048, 2048);
}